// Round 7
// baseline (3834.548 us; speedup 1.0000x reference)
//
#include <hip/hip_runtime.h>
#include <stdint.h>

// B=64, T=512, D=512, U=1024, 4U=4096
// Workspace:
//   xb : [T*64][512] bf16 = 33,554,432   (x as [t][b][d], bf16)
//   hb : u64[2][64 rows][512 pairs] = 524,288
//        word = (seq32<<32) | (h_odd<<16) | h_even   -- data carries its flag
#define WS_XB   0LL
#define WS_H    33554432LL

typedef unsigned short u16;
typedef unsigned int   u32;
typedef unsigned long long u64;
typedef __attribute__((ext_vector_type(8))) short short8;
typedef __attribute__((ext_vector_type(4))) float f32x4;

__device__ __forceinline__ u16 f2bf(float f) {
  unsigned u = __float_as_uint(f);
  u += 0x7FFFu + ((u >> 16) & 1u);   // round-to-nearest-even
  return (u16)(u >> 16);
}
__device__ __forceinline__ float fast_tanh(float x) {
  float e = __expf(2.f * x);
  return 1.f - 2.f / (e + 1.f);
}

// ---------- conv: x [64][512][512] f32 -> xb [(t*64+b)][512] bf16 ----------
__global__ void conv_x(const float* __restrict__ x, u16* __restrict__ xb) {
  long gid = (long)blockIdx.x * blockDim.x + threadIdx.x;  // 2,097,152 threads
  long sr = gid >> 6;            // source row = b*512 + t
  int  d0 = (int)(gid & 63) * 8;
  int  b = (int)(sr >> 9), t = (int)(sr & 511);
  const float* src = x + sr * 512 + d0;
  float4 v0 = *(const float4*)(src);
  float4 v1 = *(const float4*)(src + 4);
  u16 tmp[8] = {f2bf(v0.x), f2bf(v0.y), f2bf(v0.z), f2bf(v0.w),
                f2bf(v1.x), f2bf(v1.y), f2bf(v1.z), f2bf(v1.w)};
  *(short8*)(xb + ((long)t * 64 + b) * 512 + d0) = *(short8*)tmp;
}

// ---------- fused LSTM: 256 WGs = 4 batch-groups x 64 u-tiles, persistent ----------
// Exchange protocol (fence-free, flag-free):
//   writer: relaxed agent u64 stores {seq=t+1, h-pair} into buffer (t+1)&1
//   reader (top of iter t): polls ITS OWN 32 fragment words in buffer t&1
//           until every seq==t, writes frags to LDS. Detect = store travel only.
// Safety: publish over h_{t-1} slot only after consuming h_t => all peers
// published h_t => their h_{t-1} reads completed (causal). seq exact-match +
// double buffer => no ABA. t=0 reads memset zeros (seq 0, h 0) directly.
__launch_bounds__(256, 1)
__global__ void lstm_fused(const float* __restrict__ kern, const float* __restrict__ rec,
                           const u16* __restrict__ xb, u64* __restrict__ hb,
                           float* __restrict__ out) {
  __shared__ u16   smH[32 * 64 * 8];     // 32,768 B, frag-ordered
  __shared__ float zbuf[4 * 16 * 17];    //  4,352 B

  const int bid = blockIdx.x;
  const int bg = bid >> 6;   // 0..3 batch group (64 WGs each)
  const int ut = bid & 63;   // 0..63 u tile
  const int tid = threadIdx.x;
  const int w = tid >> 6, lane = tid & 63;
  const int quad = lane >> 4, n15 = lane & 15;

  // ---- one-time: 48 register B-fragments (wf[0..31]=rec K=1024, wf[32..47]=kern K=512)
  short8 wf[48];
  const size_t gcol = (size_t)w * 1024 + (size_t)ut * 16 + (size_t)n15;
#pragma unroll
  for (int ks = 0; ks < 32; ++ks) {
    u16 tmp[8];
#pragma unroll
    for (int j = 0; j < 8; ++j)
      tmp[j] = f2bf(rec[(size_t)(ks * 32 + quad * 8 + j) * 4096 + gcol]);
    wf[ks] = *(short8*)tmp;
  }
#pragma unroll
  for (int ks = 0; ks < 16; ++ks) {
    u16 tmp[8];
#pragma unroll
    for (int j = 0; j < 8; ++j)
      tmp[j] = f2bf(kern[(size_t)(ks * 32 + quad * 8 + j) * 4096 + gcol]);
    wf[32 + ks] = *(short8*)tmp;
  }

  const int bl = tid >> 4;   // elementwise: batch-local 0..15
  const int ul = tid & 15;   // elementwise: u-local 0..15
  float c = 0.f;

  // ---- prologue: x0 A-frags -> registers ----
  short8 xf[16];
  {
    const u16* xr = xb + (size_t)(bg * 16 + n15) * 512 + quad * 8;
#pragma unroll
    for (int ks = 0; ks < 16; ++ks) xf[ks] = *(const short8*)(xr + ks * 32);
  }

  for (int t = 0; t < 512; ++t) {
    // ---- A) poll-reload h_t: own fragment words, seq == t, buffer t&1 ----
    {
      const u64* hrow = hb + (size_t)(t & 1) * 32768 + (size_t)(bg * 16 + n15) * 512;
      const u32 tgt = (u32)t;
#pragma unroll
      for (int kk = 0; kk < 8; ++kk) {
        const int ks = w * 8 + kk;
        const u64* src = hrow + ks * 16 + quad * 4;
        u64 v0, v1, v2, v3;
        for (;;) {
          v0 = __hip_atomic_load(src + 0, __ATOMIC_RELAXED, __HIP_MEMORY_SCOPE_AGENT);
          v1 = __hip_atomic_load(src + 1, __ATOMIC_RELAXED, __HIP_MEMORY_SCOPE_AGENT);
          v2 = __hip_atomic_load(src + 2, __ATOMIC_RELAXED, __HIP_MEMORY_SCOPE_AGENT);
          v3 = __hip_atomic_load(src + 3, __ATOMIC_RELAXED, __HIP_MEMORY_SCOPE_AGENT);
          if ((((u32)(v0 >> 32)) == tgt) & (((u32)(v1 >> 32)) == tgt) &
              (((u32)(v2 >> 32)) == tgt) & (((u32)(v3 >> 32)) == tgt)) break;
          __builtin_amdgcn_s_sleep(1);
        }
        u32 q[4] = {(u32)v0, (u32)v1, (u32)v2, (u32)v3};
        *(uint4*)(smH + (ks * 64 + lane) * 8) = *(const uint4*)q;
      }
    }
    __syncthreads();                       // syncA: smH ready; prev zbuf reads done

    // ---- B) z = h@R (LDS frags) + x@K (reg frags), dual acc chains ----
    f32x4 acc0 = {0.f, 0.f, 0.f, 0.f}, acc1 = {0.f, 0.f, 0.f, 0.f};
#pragma unroll
    for (int ks = 0; ks < 32; ks += 2) {
      short8 a0 = *(const short8*)(smH + (ks * 64 + lane) * 8);
      acc0 = __builtin_amdgcn_mfma_f32_16x16x32_bf16(a0, wf[ks], acc0, 0, 0, 0);
      short8 a1 = *(const short8*)(smH + ((ks + 1) * 64 + lane) * 8);
      acc1 = __builtin_amdgcn_mfma_f32_16x16x32_bf16(a1, wf[ks + 1], acc1, 0, 0, 0);
    }
#pragma unroll
    for (int ks = 0; ks < 16; ks += 2) {
      acc0 = __builtin_amdgcn_mfma_f32_16x16x32_bf16(xf[ks], wf[32 + ks], acc0, 0, 0, 0);
      acc1 = __builtin_amdgcn_mfma_f32_16x16x32_bf16(xf[ks + 1], wf[33 + ks], acc1, 0, 0, 0);
    }

    // ---- C) z exchange: zbuf[gate=w][batch=quad*4+r][u=n15] ----
    float* zp = zbuf + (w * 16 + quad * 4) * 17 + n15;
    zp[0]  = acc0[0] + acc1[0];
    zp[17] = acc0[1] + acc1[1];
    zp[34] = acc0[2] + acc1[2];
    zp[51] = acc0[3] + acc1[3];
    __syncthreads();                       // syncB: z ready; frag LDS reads done

    float zi = zbuf[(0 * 16 + bl) * 17 + ul];
    float zf = zbuf[(1 * 16 + bl) * 17 + ul];
    float zg = zbuf[(2 * 16 + bl) * 17 + ul];
    float zo = zbuf[(3 * 16 + bl) * 17 + ul];
    float ig = 1.f / (1.f + __expf(-zi));
    float fg = 1.f / (1.f + __expf(-zf));
    float gg = fast_tanh(zg);
    float og = 1.f / (1.f + __expf(-zo));
    c = fg * c + ig * gg;
    float h = og * fast_tanh(c);

    if (t == 511) {
      out[(size_t)(bg * 16 + bl) * 1024 + (size_t)ut * 16 + ul] = h;
      break;
    }

    // ---- D) publish h_{t+1}: u64 {seq, pair} relaxed stores (no ack, no flag) ----
    {
      u16 hu = f2bf(h);
      int other = __shfl_xor((int)(unsigned)hu, 1);
      if ((tid & 1) == 0) {
        u64 v = ((u64)(u32)(t + 1) << 32) | ((u64)(u32)(unsigned)other << 16) | (u64)hu;
        __hip_atomic_store(hb + (size_t)((t + 1) & 1) * 32768
                              + (size_t)(bg * 16 + bl) * 512 + ut * 8 + (ul >> 1),
                           v, __ATOMIC_RELAXED, __HIP_MEMORY_SCOPE_AGENT);
      }
    }

    // ---- E) x_{t+1} A-frag prefetch (L2-cached; overlaps next poll) ----
    {
      const u16* xr = xb + ((size_t)(t + 1) * 64 + bg * 16 + n15) * 512 + quad * 8;
#pragma unroll
      for (int ks = 0; ks < 16; ++ks) xf[ks] = *(const short8*)(xr + ks * 32);
    }
  }
}

extern "C" void kernel_launch(void* const* d_in, const int* in_sizes, int n_in,
                              void* d_out, int out_size, void* d_ws, size_t ws_size,
                              hipStream_t stream) {
  const float* x    = (const float*)d_in[0];
  const float* kern = (const float*)d_in[1];
  const float* rec  = (const float*)d_in[2];
  float* out = (float*)d_out;
  char* ws = (char*)d_ws;

  u16* xbp = (u16*)(ws + WS_XB);
  u64* hb  = (u64*)(ws + WS_H);

  // zero h seq-buffer (doubles as h0 = 0 with seq 0); ws re-poisoned each call
  hipMemsetAsync(ws + WS_H, 0, 524288, stream);

  conv_x<<<8192, 256, 0, stream>>>(x, xbp);

  lstm_fused<<<256, 256, 0, stream>>>(kern, rec, xbp, hb, out);
}